// Round 12
// baseline (249.009 us; speedup 1.0000x reference)
//
#include <hip/hip_runtime.h>
#include <hip/hip_bf16.h>
#include <cstdint>

#define SEQ 2048
#define NH  16
#define HD  64
#define DM  1024
#define BATCH 2

typedef unsigned short ushort_t;
typedef __attribute__((ext_vector_type(8))) short short8;   // bf16x8 MFMA frag (4 VGPRs)
typedef __attribute__((ext_vector_type(4))) float f32x4;    // fp32x4 accum

__device__ __forceinline__ ushort_t f2bf(float f){
  __hip_bfloat16 h = __float2bfloat16(f);
  return *reinterpret_cast<ushort_t*>(&h);
}
__device__ __forceinline__ ushort_t f2bf_fast(float f){
  uint32_t u = __float_as_uint(f);
  u += 0x7FFF + ((u >> 16) & 1);
  return (ushort_t)(u >> 16);
}

#define GLDS(g, l) __builtin_amdgcn_global_load_lds( \
    (const __attribute__((address_space(1))) void*)(g), \
    (__attribute__((address_space(3))) void*)(l), 16, 0, 0)

// ====== RoPE trig table, [j][t] layout: tab[(j*SEQ+t)*2] = {cos,sin}(t*invf[j])
__device__ __forceinline__ void rope_tab_elem(float* __restrict__ tab, int idx){
  int t = idx & 2047, j = idx >> 11;
  float invf = exp2f(-(float)j * 0.41524101186092033f);
  float sn, cn;
  sincosf((float)t * invf, &sn, &cn);
  tab[2*idx]   = cn;     // idx = j*2048 + t
  tab[2*idx+1] = sn;
}

__global__ __launch_bounds__(256) void rope_tab_kernel(float* __restrict__ tab){
  rope_tab_elem(tab, blockIdx.x * 256 + threadIdx.x);
}

// ================= prep (big-ws): fp32->bf16 cvt + rope table, one launch ====
__global__ __launch_bounds__(256) void prep_kernel(
    const float* __restrict__ x,  const float* __restrict__ Wq,
    const float* __restrict__ Wk, const float* __restrict__ Wv,
    const float* __restrict__ Wo,
    ushort_t* __restrict__ xb,  ushort_t* __restrict__ wqb,
    ushort_t* __restrict__ wkb, ushort_t* __restrict__ wvb,
    ushort_t* __restrict__ wob, float* __restrict__ tab)
{
  int bid = blockIdx.x;
  if(bid >= 8192){                              // tail 256 blocks: trig table
    rope_tab_elem(tab, (bid - 8192) * 256 + threadIdx.x);
    return;
  }
  int f = bid * 256 + threadIdx.x;              // 0..2M-1 float4s
  const float* s; ushort_t* d; int off;
  if(f < (1<<20)){ s = x; d = xb; off = f; }
  else{
    int r = f - (1<<20);
    int w = r >> 18;
    off = r & ((1<<18)-1);
    s = (w==0)?Wq:(w==1)?Wk:(w==2)?Wv:Wo;
    d = (w==0)?wqb:(w==1)?wkb:(w==2)?wvb:wob;
  }
  float4 v = *reinterpret_cast<const float4*>(s + (size_t)off*4);
  ushort_t t[4] = {f2bf(v.x), f2bf(v.y), f2bf(v.z), f2bf(v.w)};
  *reinterpret_cast<uint2*>(d + (size_t)off*4) = *reinterpret_cast<const uint2*>(t);
}

// ================= 128x128 bf16 GEMM core, 2-phase double-buffered ===========
// SWAP=true flips MFMA operands: acc col(l16)=m(token), row(quad*4+r)=n(feat).
template<bool SWAP>
__device__ __forceinline__ void gemm_core_bf16_glds(
    const ushort_t* __restrict__ A, const ushort_t* __restrict__ B,
    ushort_t* As, ushort_t* Bs,    // each [2][128*32]
    int m0, int n0, f32x4 acc[4][4])
{
  const int tid  = threadIdx.x;
  const int lane = tid & 63;
  const int wave = tid >> 6;
  const int quad = lane >> 4, l16 = lane & 15;
  const int wm = (wave >> 1) * 64, wn = (wave & 1) * 64;

  const int srow0 = tid >> 2, sseg0 = tid & 3;

  #define STAGE_BF16(k0, hb) { \
    _Pragma("unroll") \
    for(int u = 0; u < 2; u++){ \
      int idx = tid + u * 256; \
      int row = srow0 + u * 64, seg = sseg0; \
      int col = (seg ^ (row & 3)) * 8; \
      ushort_t* la = &As[(hb)*4096 + (size_t)(idx & ~63) * 8]; \
      ushort_t* lb = &Bs[(hb)*4096 + (size_t)(idx & ~63) * 8]; \
      GLDS(&A[(size_t)(m0+row)*DM + (k0) + col], la); \
      GLDS(&B[(size_t)(n0+row)*DM + (k0) + col], lb); \
    } }

  STAGE_BF16(0, 0);
  __syncthreads();
  int cur = 0;
  for(int k0 = 0; k0 < DM; k0 += 32){
    if(k0 + 32 < DM) STAGE_BF16(k0 + 32, cur ^ 1);
    const ushort_t* as = &As[cur*4096];
    const ushort_t* bs = &Bs[cur*4096];
    short8 af[4], bf[4];
    #pragma unroll
    for(int mt=0;mt<4;mt++){
      int row = wm + mt*16 + l16;
      af[mt] = *reinterpret_cast<const short8*>(&as[row*32 + (quad ^ (row&3))*8]);
    }
    #pragma unroll
    for(int nt=0;nt<4;nt++){
      int row = wn + nt*16 + l16;
      bf[nt] = *reinterpret_cast<const short8*>(&bs[row*32 + (quad ^ (row&3))*8]);
    }
    #pragma unroll
    for(int mt=0;mt<4;mt++)
      #pragma unroll
      for(int nt=0;nt<4;nt++)
        acc[mt][nt] = SWAP
          ? __builtin_amdgcn_mfma_f32_16x16x32_bf16(bf[nt], af[mt], acc[mt][nt], 0, 0, 0)
          : __builtin_amdgcn_mfma_f32_16x16x32_bf16(af[mt], bf[nt], acc[mt][nt], 0, 0, 0);
    __syncthreads();
    cur ^= 1;
  }
  #undef STAGE_BF16
}

// f32 fallback core (small-ws path only)
template<bool SWAP>
__device__ __forceinline__ void gemm_core_f32(
    const float* __restrict__ A, const float* __restrict__ B,
    ushort_t* As, ushort_t* Bs, int m0, int n0, f32x4 acc[4][4])
{
  const int tid  = threadIdx.x;
  const int lane = tid & 63;
  const int wave = tid >> 6;
  const int quad = lane >> 4, l16 = lane & 15;
  const int wm = (wave >> 1) * 64, wn = (wave & 1) * 64;
  for(int k0 = 0; k0 < DM; k0 += 32){
    #pragma unroll
    for(int u = 0; u < 4; u++){
      int idx = tid + u * 256;
      int row = idx >> 3, seg = idx & 7;
      float4 av = *reinterpret_cast<const float4*>(&A[(size_t)(m0+row)*DM + k0 + seg*4]);
      float4 bv = *reinterpret_cast<const float4*>(&B[(size_t)(n0+row)*DM + k0 + seg*4]);
      ushort_t at[4] = {f2bf(av.x), f2bf(av.y), f2bf(av.z), f2bf(av.w)};
      ushort_t bt[4] = {f2bf(bv.x), f2bf(bv.y), f2bf(bv.z), f2bf(bv.w)};
      *reinterpret_cast<uint2*>(&As[row*40 + seg*4]) = *reinterpret_cast<const uint2*>(at);
      *reinterpret_cast<uint2*>(&Bs[row*40 + seg*4]) = *reinterpret_cast<const uint2*>(bt);
    }
    __syncthreads();
    short8 af[4], bf[4];
    #pragma unroll
    for(int mt=0;mt<4;mt++) af[mt] = *reinterpret_cast<const short8*>(&As[(wm+mt*16+l16)*40 + quad*8]);
    #pragma unroll
    for(int nt=0;nt<4;nt++) bf[nt] = *reinterpret_cast<const short8*>(&Bs[(wn+nt*16+l16)*40 + quad*8]);
    #pragma unroll
    for(int mt=0;mt<4;mt++)
      #pragma unroll
      for(int nt=0;nt<4;nt++)
        acc[mt][nt] = SWAP
          ? __builtin_amdgcn_mfma_f32_16x16x32_bf16(bf[nt], af[mt], acc[mt][nt], 0, 0, 0)
          : __builtin_amdgcn_mfma_f32_16x16x32_bf16(af[mt], bf[nt], acc[mt][nt], 0, 0, 0);
    __syncthreads();
  }
}

// ================= QKV epilogue (all-SWAP): in-thread RoPE ===================
__device__ __forceinline__ void qkv_epilogue_swap(
    int z, int m0, int n0, f32x4 acc[4][4], const float* __restrict__ tab,
    ushort_t* __restrict__ Q, ushort_t* __restrict__ Ko, ushort_t* __restrict__ Vt)
{
  const int lane = threadIdx.x & 63;
  const int wave = threadIdx.x >> 6;
  const int quad = lane >> 4, l16 = lane & 15;
  const int wm = (wave >> 1) * 64, wn = (wave & 1) * 64;
  if(z < 2){
    ushort_t* outp = (z == 0) ? Q : Ko;
    const float qscale = (z == 0) ? 0.125f : 1.0f;   // fold 1/sqrt(64) into Q
    #pragma unroll
    for(int mt=0;mt<4;mt++){
      int m = m0 + wm + mt*16 + l16;      // token
      int b = m >> 11, s = m & 2047;
      #pragma unroll
      for(int nt=0;nt<4;nt++){
        int nbase = n0 + wn + nt*16 + quad*4;   // 4-aligned feature base
        int h  = nbase >> 6, dhb = nbase & 63;
        int jb = dhb & 31;                       // jb..jb+3, no 32-wrap
        float v0 = acc[mt][nt][0], v1 = acc[mt][nt][1];
        float v2 = acc[mt][nt][2], v3 = acc[mt][nt][3];
        float2 cs0 = *reinterpret_cast<const float2*>(&tab[((jb  )*SEQ + s)*2]);
        float2 cs1 = *reinterpret_cast<const float2*>(&tab[((jb+1)*SEQ + s)*2]);
        float2 cs2 = *reinterpret_cast<const float2*>(&tab[((jb+2)*SEQ + s)*2]);
        float2 cs3 = *reinterpret_cast<const float2*>(&tab[((jb+3)*SEQ + s)*2]);
        float oe0 = (v0*cs0.x - v1*cs0.y) * qscale;   // -> outd = dhb/2
        float oo0 = (v0*cs1.y + v1*cs1.x) * qscale;   // -> outd = dhb/2 + 32
        float oe1 = (v2*cs2.x - v3*cs2.y) * qscale;   // -> outd = dhb/2 + 1
        float oo1 = (v2*cs3.y + v3*cs3.x) * qscale;   // -> outd = dhb/2 + 33
        int d2 = dhb >> 1;                             // even
        size_t base = ((size_t)(b*NH + h)*SEQ + s)*HD;
        uint32_t lo = (uint32_t)f2bf_fast(oe0) | ((uint32_t)f2bf_fast(oe1) << 16);
        uint32_t hi = (uint32_t)f2bf_fast(oo0) | ((uint32_t)f2bf_fast(oo1) << 16);
        *reinterpret_cast<uint32_t*>(&outp[base + d2])      = lo;
        *reinterpret_cast<uint32_t*>(&outp[base + d2 + 32]) = hi;
      }
    }
  } else {
    // V^T: col(l16)=token -> 32B-contiguous token segments per (nt,mt,r)
    #pragma unroll
    for(int nt=0;nt<4;nt++){
      #pragma unroll
      for(int mt=0;mt<4;mt++){
        int m = m0 + wm + mt*16 + l16;
        int b = m >> 11, s = m & 2047;
        #pragma unroll
        for(int r=0;r<4;r++){
          int n = n0 + wn + nt*16 + quad*4 + r;
          int h = n >> 6, dh = n & 63;
          Vt[((size_t)(b*NH + h)*HD + dh)*SEQ + s] = f2bf_fast(acc[mt][nt][r]);
        }
      }
    }
  }
}

__global__ __launch_bounds__(256) void qkv_bf16_kernel(
    const ushort_t* __restrict__ xb,
    const ushort_t* __restrict__ wqb, const ushort_t* __restrict__ wkb,
    const ushort_t* __restrict__ wvb, const float* __restrict__ tab,
    ushort_t* __restrict__ Q, ushort_t* __restrict__ Ko, ushort_t* __restrict__ Vt)
{
  const int z = blockIdx.z;
  const ushort_t* W = (z == 0) ? wqb : (z == 1) ? wkb : wvb;
  const int m0 = blockIdx.x * 128, n0 = blockIdx.y * 128;
  __shared__ __align__(16) ushort_t As[2*128*32];
  __shared__ __align__(16) ushort_t Bs[2*128*32];
  f32x4 acc[4][4];
  #pragma unroll
  for(int i=0;i<4;i++)
    #pragma unroll
    for(int j=0;j<4;j++) acc[i][j] = (f32x4){0.f,0.f,0.f,0.f};
  gemm_core_bf16_glds<true>(xb, W, As, Bs, m0, n0, acc);
  qkv_epilogue_swap(z, m0, n0, acc, tab, Q, Ko, Vt);
}

__global__ __launch_bounds__(256) void qkv_f32_kernel(
    const float* __restrict__ x,
    const float* __restrict__ Wq, const float* __restrict__ Wk,
    const float* __restrict__ Wv, const float* __restrict__ tab,
    ushort_t* __restrict__ Q, ushort_t* __restrict__ Ko, ushort_t* __restrict__ Vt)
{
  const int z = blockIdx.z;
  const float* W = (z == 0) ? Wq : (z == 1) ? Wk : Wv;
  const int m0 = blockIdx.x * 128, n0 = blockIdx.y * 128;
  __shared__ __align__(16) char smem[20480];
  ushort_t* As = (ushort_t*)smem;
  ushort_t* Bs = (ushort_t*)(smem + 10240);
  f32x4 acc[4][4];
  #pragma unroll
  for(int i=0;i<4;i++)
    #pragma unroll
    for(int j=0;j<4;j++) acc[i][j] = (f32x4){0.f,0.f,0.f,0.f};
  gemm_core_f32<true>(x, W, As, Bs, m0, n0, acc);
  qkv_epilogue_swap(z, m0, n0, acc, tab, Q, Ko, Vt);
}

// ================= Flash attention, causal — 32 q rows per wave ==============
// Round-12: REVERT to the round-7 proven kernel (79.6 µs clean: VGPR 108,
// WRITE 8MB) — the 16q occupancy arc (r8-r11) is dead: the allocator's
// occupancy heuristic caps the 16q body at ~50 VGPR and spills ~100MB
// regardless of LDS size or launch_bounds. The 32q body reproducibly gets
// 108 VGPR, no spill.
// Single new variable vs r7: s_setprio(1)/(0) around the QK and PV MFMA
// clusters (T5). Mechanism: 2 independent blocks/CU at different loop phases
// (different T, never cross-synced) = wave role-diversity; guide measured
// +4-7% on attn in this regime (m191), null only for lockstep waves (m190).
__global__ __launch_bounds__(256) void attn_kernel(
    ushort_t* __restrict__ Qbuf, const ushort_t* __restrict__ K,
    const ushort_t* __restrict__ Vt)
{
  const int bh = blockIdx.x;            // 0..31
  const int y  = blockIdx.y;            // 0..15
  const int g  = (y < 8) ? (15 - y) : (y - 8);
  const int T  = 2*(g+1);               // 64-kv rounds
  const int tid  = threadIdx.x;
  const int lane = tid & 63;
  const int wave = tid >> 6;            // 0..3
  const int quad = lane >> 4, l16 = lane & 15;

  ushort_t*       Qp = Qbuf + (size_t)bh * SEQ * HD;
  const ushort_t* Kp = K    + (size_t)bh * SEQ * HD;
  const ushort_t* Vp = Vt   + (size_t)bh * HD * SEQ;

  __shared__ __align__(16) ushort_t Ks[2][64*72];
  __shared__ __align__(16) ushort_t Vs[2][64*72];
  __shared__ __align__(16) ushort_t Pl[4][32*72];   // per-wave P roundtrip
  ushort_t* pl = &Pl[wave][0];

  const int srow0 = tid >> 3;           // staging row 0..31 (+32 for u=1)
  const int scol  = (tid & 7) * 8;      // 16B chunk col

  const int q0w = 128*g + 32*wave;      // this wave's 32 q rows

  // Q fragments (B-operand), 2 sets x 2 kk, from global once
  short8 qf[2][2];
  #pragma unroll
  for(int s=0;s<2;s++)
    #pragma unroll
    for(int kk=0;kk<2;kk++)
      qf[s][kk] = *reinterpret_cast<const short8*>(&Qp[(size_t)(q0w + 16*s + l16)*HD + kk*32 + quad*8]);

  f32x4 oacc[2][4];
  #pragma unroll
  for(int s=0;s<2;s++)
    #pragma unroll
    for(int dt=0;dt<4;dt++) oacc[s][dt] = (f32x4){0.f,0.f,0.f,0.f};
  float llane[2] = {0.f, 0.f};

  // prologue: tile 0 -> regs -> buf0; prefetch tile 1 -> regs
  uint4 kreg[2], vreg[2];
  #pragma unroll
  for(int u=0;u<2;u++){
    int row = srow0 + u*32;
    kreg[u] = *reinterpret_cast<const uint4*>(&Kp[(size_t)row*HD + scol]);
    vreg[u] = *reinterpret_cast<const uint4*>(&Vp[(size_t)row*SEQ + scol]);
  }
  #pragma unroll
  for(int u=0;u<2;u++){
    int row = srow0 + u*32;
    *reinterpret_cast<uint4*>(&Ks[0][row*72 + scol]) = kreg[u];
    *reinterpret_cast<uint4*>(&Vs[0][row*72 + scol]) = vreg[u];
  }
  if(T > 1){
    #pragma unroll
    for(int u=0;u<2;u++){
      int row = srow0 + u*32;
      kreg[u] = *reinterpret_cast<const uint4*>(&Kp[(size_t)(64 + row)*HD + scol]);
      vreg[u] = *reinterpret_cast<const uint4*>(&Vp[(size_t)row*SEQ + 64 + scol]);
    }
  }
  __syncthreads();    // buf0 visible

  for(int t = 0; t < T; t++){
    const int kv0 = t * 64;
    const int cur = t & 1;

    // K/V fragments from current buffer — issued first (critical path)
    short8 kf[4][2], vf[4][2];
    #pragma unroll
    for(int nt=0;nt<4;nt++)
      #pragma unroll
      for(int kk=0;kk<2;kk++)
        kf[nt][kk] = *reinterpret_cast<const short8*>(&Ks[cur][(nt*16 + l16)*72 + kk*32 + quad*8]);
    #pragma unroll
    for(int dt=0;dt<4;dt++)
      #pragma unroll
      for(int kk=0;kk<2;kk++)
        vf[dt][kk] = *reinterpret_cast<const short8*>(&Vs[cur][(dt*16 + l16)*72 + kk*32 + quad*8]);

    // stage tile t+1 (regs -> other buffer); overlaps with compute below
    if(t + 1 < T){
      #pragma unroll
      for(int u=0;u<2;u++){
        int row = srow0 + u*32;
        *reinterpret_cast<uint4*>(&Ks[cur^1][row*72 + scol]) = kreg[u];
        *reinterpret_cast<uint4*>(&Vs[cur^1][row*72 + scol]) = vreg[u];
      }
    }
    // prefetch tile t+2 globals into regs (regs free after the ds_writes)
    if(t + 2 < T){
      #pragma unroll
      for(int u=0;u<2;u++){
        int row = srow0 + u*32;
        kreg[u] = *reinterpret_cast<const uint4*>(&Kp[(size_t)(kv0 + 128 + row)*HD + scol]);
        vreg[u] = *reinterpret_cast<const uint4*>(&Vp[(size_t)row*SEQ + kv0 + 128 + scol]);
      }
    }

    #pragma unroll
    for(int s=0;s<2;s++){
      // S^T = K·(Q/8)^T : col=q=l16, row=kv=quad*4+r (block nt*16)
      f32x4 sacc[4];
      #pragma unroll
      for(int nt=0;nt<4;nt++) sacc[nt] = (f32x4){0.f,0.f,0.f,0.f};
      __builtin_amdgcn_s_setprio(1);
      #pragma unroll
      for(int kk=0;kk<2;kk++)
        #pragma unroll
        for(int nt=0;nt<4;nt++)
          sacc[nt] = __builtin_amdgcn_mfma_f32_16x16x32_bf16(kf[nt][kk], qf[s][kk], sacc[nt], 0,0,0);
      __builtin_amdgcn_s_setprio(0);

      const int q_abs = q0w + 16*s + l16;
      const bool maskable = (kv0 + 63 > q0w + 16*s);   // wave-uniform
      float pv[4][4];
      #pragma unroll
      for(int nt=0;nt<4;nt++)
        #pragma unroll
        for(int r=0;r<4;r++){
          float sv = sacc[nt][r];
          if(maskable){
            int kv_abs = kv0 + nt*16 + quad*4 + r;
            sv = (kv_abs > q_abs) ? -1e30f : sv;
          }
          float p = __expf(sv);
          pv[nt][r] = p;
          llane[s] += p;
        }

      // P^T -> per-wave LDS rows 16s..16s+15 (packed b64; same-wave DS order)
      asm volatile("" ::: "memory");
      #pragma unroll
      for(int nt=0;nt<4;nt++){
        uint32_t lo = (uint32_t)f2bf_fast(pv[nt][0]) | ((uint32_t)f2bf_fast(pv[nt][1]) << 16);
        uint32_t hi = (uint32_t)f2bf_fast(pv[nt][2]) | ((uint32_t)f2bf_fast(pv[nt][3]) << 16);
        uint2 pk; pk.x = lo; pk.y = hi;
        *reinterpret_cast<uint2*>(&pl[(16*s + l16)*72 + nt*16 + quad*4]) = pk;
      }
      asm volatile("s_waitcnt lgkmcnt(0)" ::: "memory");

      // PV: out^T += V^T·P^T
      __builtin_amdgcn_s_setprio(1);
      #pragma unroll
      for(int kk=0;kk<2;kk++){
        short8 pf = *reinterpret_cast<const short8*>(&pl[(16*s + l16)*72 + kk*32 + quad*8]);
        #pragma unroll
        for(int dt=0;dt<4;dt++)
          oacc[s][dt] = __builtin_amdgcn_mfma_f32_16x16x32_bf16(vf[dt][kk], pf, oacc[s][dt], 0,0,0);
      }
      __builtin_amdgcn_s_setprio(0);
    }
    __syncthreads();   // all waves done reading buf[cur]; buf[cur^1] staged
  }

  // epilogue: cross-quad l reduce per set, normalize, packed 8B stores
  #pragma unroll
  for(int s=0;s<2;s++){
    float lt = llane[s];
    lt += __shfl_xor(lt, 16);
    lt += __shfl_xor(lt, 32);
    float inv = 1.0f / lt;
    #pragma unroll
    for(int dt=0;dt<4;dt++){
      uint32_t lo = (uint32_t)f2bf_fast(oacc[s][dt][0] * inv) | ((uint32_t)f2bf_fast(oacc[s][dt][1] * inv) << 16);
      uint32_t hi = (uint32_t)f2bf_fast(oacc[s][dt][2] * inv) | ((uint32_t)f2bf_fast(oacc[s][dt][3] * inv) << 16);
      uint2 pk; pk.x = lo; pk.y = hi;
      *reinterpret_cast<uint2*>(&Qp[(size_t)(q0w + 16*s + l16)*HD + dt*16 + quad*4]) = pk;
    }
  }
}

// ================= Output projection (2-phase glds staging) =================
__global__ __launch_bounds__(256) void out_proj_bf16_kernel(
    const ushort_t* __restrict__ ctx, const ushort_t* __restrict__ wob,
    float* __restrict__ out)
{
  const int m0 = blockIdx.x * 128, n0 = blockIdx.y * 128;
  __shared__ __align__(16) ushort_t As[2*128*32];
  __shared__ __align__(16) ushort_t Bs[2*128*32];
  const int tid  = threadIdx.x;
  const int lane = tid & 63;
  const int wave = tid >> 6;
  const int quad = lane >> 4, l16 = lane & 15;
  const int wm = (wave >> 1) * 64, wn = (wave & 1) * 64;
  const int srow0 = tid >> 2, sseg0 = tid & 3;

  f32x4 acc[4][4];
  #pragma unroll
  for(int i=0;i<4;i++)
    #pragma unroll
    for(int j=0;j<4;j++) acc[i][j] = (f32x4){0.f,0.f,0.f,0.f};

  #define STAGE_OP(k0, hb) { \
    const int head = (k0) >> 6, off = (k0) & 63; \
    _Pragma("unroll") \
    for(int u = 0; u < 2; u++){ \
      int idx = tid + u * 256; \
      int row = srow0 + u * 64, seg = sseg0; \
      int col = (seg ^ (row & 3)) * 8; \
      int m = m0 + row, b = m >> 11, s = m & 2047; \
      ushort_t* la = &As[(hb)*4096 + (size_t)(idx & ~63) * 8]; \
      ushort_t* lb = &Bs[(hb)*4096 + (size_t)(idx & ~63) * 8]; \
      GLDS(&ctx[((size_t)(b*NH + head)*SEQ + s)*HD + off + col], la); \
      GLDS(&wob[(size_t)(n0+row)*DM + (k0) + col], lb); \
    } }

  STAGE_OP(0, 0);
  __syncthreads();
  int cur = 0;
  for(int k0 = 0; k0 < DM; k0 += 32){
    if(k0 + 32 < DM) STAGE_OP(k0 + 32, cur ^ 1);
    const ushort_t* as = &As[cur*4096];
    const ushort_t* bs = &Bs[cur*4096];
    short8 af[4], bf[4];
    #pragma unroll
    for(int mt=0;mt<4;mt++){
      int row = wm + mt*16 + l16;
      af[mt] = *reinterpret_cast<const short8*>(&as[row*32 + (quad ^ (row&3))*8]);
    }
    #pragma unroll
    for(int nt=0;nt<4;nt++){
      int row = wn + nt*16 + l16;
      bf[nt] = *reinterpret_cast<const short8*>(&bs[row*32 + (quad ^ (row&3))*8]);
    }
    #pragma unroll
    for(int mt=0;mt<4;mt++)
      #pragma unroll
      for(int nt=0;nt<4;nt++)
        acc[mt][nt] = __builtin_amdgcn_mfma_f32_16x16x32_bf16(af[mt], bf[nt], acc[mt][nt], 0, 0, 0);
    __syncthreads();
    cur ^= 1;
  }
  #undef STAGE_OP

  #pragma unroll
  for(int mt=0;mt<4;mt++)
    #pragma unroll
    for(int nt=0;nt<4;nt++)
      #pragma unroll
      for(int r=0;r<4;r++){
        int m = m0 + wm + mt*16 + quad*4 + r;
        int n = n0 + wn + nt*16 + l16;
        out[(size_t)m*DM + n] = acc[mt][nt][r];
      }
}

__global__ __launch_bounds__(256) void out_proj_f32_kernel(
    const ushort_t* __restrict__ ctx, const float* __restrict__ Wo,
    float* __restrict__ out)
{
  const int m0 = blockIdx.x * 128, n0 = blockIdx.y * 128;
  __shared__ __align__(16) ushort_t As[128*40];
  __shared__ __align__(16) ushort_t Bs[128*40];
  const int tid  = threadIdx.x;
  const int lane = tid & 63;
  const int wave = tid >> 6;
  const int quad = lane >> 4, l16 = lane & 15;
  const int wm = (wave >> 1) * 64, wn = (wave & 1) * 64;

  f32x4 acc[4][4];
  #pragma unroll
  for(int i=0;i<4;i++)
    #pragma unroll
    for(int j=0;j<4;j++) acc[i][j] = (f32x4){0.f,0.f,0.f,0.f};

  for(int k0 = 0; k0 < DM; k0 += 32){
    const int head = k0 >> 6, off = k0 & 63;
    #pragma unroll
    for(int u = 0; u < 2; u++){
      int idx = tid + u * 256;
      int row = idx >> 2, seg = idx & 3;
      int m = m0 + row, b = m >> 11, s = m & 2047;
      *reinterpret_cast<uint4*>(&As[row*40 + seg*8]) =
        *reinterpret_cast<const uint4*>(&ctx[((size_t)(b*NH + head)*SEQ + s)*HD + off + seg*8]);
    }
    #pragma unroll
    for(int u = 0; u < 4; u++){
      int idx = tid + u * 256;
      int row = idx >> 3, seg = idx & 7;
      float4 bv = *reinterpret_cast<const float4*>(&Wo[(size_t)(n0+row)*DM + k0 + seg*4]);
      ushort_t bt[4] = {f2bf(bv.x), f2bf(bv.y), f2bf(bv.z), f2bf(bv.w)};
      *reinterpret_cast<uint2*>(&Bs[row*40 + seg*4]) = *reinterpret_cast<const uint2*>(bt);
    }
    __syncthreads();
    short8 af[4], bf[4];
    #pragma unroll
    for(int mt=0;mt<4;mt++) af[mt] = *reinterpret_cast<const short8*>(&As[(wm+mt*16+l16)*40 + quad*8]);
    #pragma unroll
    for(int nt=0;nt<4;nt++) bf[nt] = *reinterpret_cast<const short8*>(&Bs[(wn+nt*16+l16)*40 + quad*8]);
    #pragma unroll
    for(int mt=0;mt<4;mt++)
      #pragma unroll
      for(int nt=0;nt<4;nt++)
        acc[mt][nt] = __builtin_amdgcn_mfma_f32_16x16x32_bf16(af[mt], bf[nt], acc[mt][nt], 0, 0, 0);
    __syncthreads();
  }
  #pragma unroll
  for(int mt=0;mt<4;mt++)
    #pragma unroll
    for(int nt=0;nt<4;nt++)
      #pragma unroll
      for(int r=0;r<4;r++){
        int m = m0 + wm + mt*16 + quad*4 + r;
        int n = n0 + wn + nt*16 + l16;
        out[(size_t)m*DM + n] = acc[mt][nt][r];
      }
}

extern "C" void kernel_launch(void* const* d_in, const int* in_sizes, int n_in,
                              void* d_out, int out_size, void* d_ws, size_t ws_size,
                              hipStream_t stream) {
  const float* x  = (const float*)d_in[0];
  const float* Wq = (const float*)d_in[1];
  const float* Wk = (const float*)d_in[2];
  const float* Wv = (const float*)d_in[3];
  const float* Wo = (const float*)d_in[4];
  // d_in[5] = attn_mask (tril int32) — implemented positionally as causal.
  float* out = (float*)d_out;

  // ws: Qb 8MB (Q -> ctx in-place) + trig 512KB; big path adds xb + bf16 weights.
  // d_out (16MB fp32): K + V^T bf16 scratch, dead before out_proj writes.
  char* ws = (char*)d_ws;
  ushort_t* Qb  = (ushort_t*)ws;                              // 8 MB
  float*    tab = (float*)(ws + (8u << 20));                  // 512 KB
  ushort_t* Kb  = (ushort_t*)d_out;                           // 8 MB
  ushort_t* Vt  = (ushort_t*)d_out + (size_t)BATCH*NH*SEQ*HD; // 8 MB

  const bool big_ws = ws_size >= (25u << 20);

  if(big_ws){
    ushort_t* xb  = (ushort_t*)(ws + (8u  << 20) + (512u << 10));   // 8 MB
    char*     wb0 = ws + (16u << 20) + (512u << 10);
    ushort_t* wqb = (ushort_t*)(wb0);
    ushort_t* wkb = (ushort_t*)(wb0 + (2u << 20));
    ushort_t* wvb = (ushort_t*)(wb0 + (4u << 20));
    ushort_t* wob = (ushort_t*)(wb0 + (6u << 20));
    prep_kernel<<<8448, 256, 0, stream>>>(x, Wq, Wk, Wv, Wo, xb, wqb, wkb, wvb, wob, tab);
    dim3 g1(32, 8, 3);
    qkv_bf16_kernel<<<g1, 256, 0, stream>>>(xb, wqb, wkb, wvb, tab, Qb, Kb, Vt);
    dim3 g2(32, 16);   // (bh, y): XCD affinity + g-paired balance (r7 grid)
    attn_kernel<<<g2, 256, 0, stream>>>(Qb, Kb, Vt);
    dim3 g3(32, 8);
    out_proj_bf16_kernel<<<g3, 256, 0, stream>>>(Qb, wob, out);
  } else {
    rope_tab_kernel<<<256, 256, 0, stream>>>(tab);
    dim3 g1(32, 8, 3);
    qkv_f32_kernel<<<g1, 256, 0, stream>>>(x, Wq, Wk, Wv, tab, Qb, Kb, Vt);
    dim3 g2(32, 16);
    attn_kernel<<<g2, 256, 0, stream>>>(Qb, Kb, Vt);
    dim3 g3(32, 8);
    out_proj_f32_kernel<<<g3, 256, 0, stream>>>(Qb, Wo, out);
  }
}

// Round 13
// 235.675 us; speedup vs baseline: 1.0566x; 1.0566x over previous
//
#include <hip/hip_runtime.h>
#include <hip/hip_bf16.h>
#include <cstdint>

#define SEQ 2048
#define NH  16
#define HD  64
#define DM  1024
#define BATCH 2

typedef unsigned short ushort_t;
typedef __attribute__((ext_vector_type(8))) short short8;   // bf16x8 MFMA frag (4 VGPRs)
typedef __attribute__((ext_vector_type(4))) float f32x4;    // fp32x4 accum

__device__ __forceinline__ ushort_t f2bf(float f){
  __hip_bfloat16 h = __float2bfloat16(f);
  return *reinterpret_cast<ushort_t*>(&h);
}
__device__ __forceinline__ ushort_t f2bf_fast(float f){
  uint32_t u = __float_as_uint(f);
  u += 0x7FFF + ((u >> 16) & 1);
  return (ushort_t)(u >> 16);
}

#define GLDS(g, l) __builtin_amdgcn_global_load_lds( \
    (const __attribute__((address_space(1))) void*)(g), \
    (__attribute__((address_space(3))) void*)(l), 16, 0, 0)

// ====== RoPE trig table, [j][t] layout: tab[(j*SEQ+t)*2] = {cos,sin}(t*invf[j])
__device__ __forceinline__ void rope_tab_elem(float* __restrict__ tab, int idx){
  int t = idx & 2047, j = idx >> 11;
  float invf = exp2f(-(float)j * 0.41524101186092033f);
  float sn, cn;
  sincosf((float)t * invf, &sn, &cn);
  tab[2*idx]   = cn;     // idx = j*2048 + t
  tab[2*idx+1] = sn;
}

__global__ __launch_bounds__(256) void rope_tab_kernel(float* __restrict__ tab){
  rope_tab_elem(tab, blockIdx.x * 256 + threadIdx.x);
}

// ================= prep (big-ws): fp32->bf16 cvt + rope table, one launch ====
__global__ __launch_bounds__(256) void prep_kernel(
    const float* __restrict__ x,  const float* __restrict__ Wq,
    const float* __restrict__ Wk, const float* __restrict__ Wv,
    const float* __restrict__ Wo,
    ushort_t* __restrict__ xb,  ushort_t* __restrict__ wqb,
    ushort_t* __restrict__ wkb, ushort_t* __restrict__ wvb,
    ushort_t* __restrict__ wob, float* __restrict__ tab)
{
  int bid = blockIdx.x;
  if(bid >= 8192){                              // tail 256 blocks: trig table
    rope_tab_elem(tab, (bid - 8192) * 256 + threadIdx.x);
    return;
  }
  int f = bid * 256 + threadIdx.x;              // 0..2M-1 float4s
  const float* s; ushort_t* d; int off;
  if(f < (1<<20)){ s = x; d = xb; off = f; }
  else{
    int r = f - (1<<20);
    int w = r >> 18;
    off = r & ((1<<18)-1);
    s = (w==0)?Wq:(w==1)?Wk:(w==2)?Wv:Wo;
    d = (w==0)?wqb:(w==1)?wkb:(w==2)?wvb:wob;
  }
  float4 v = *reinterpret_cast<const float4*>(s + (size_t)off*4);
  ushort_t t[4] = {f2bf(v.x), f2bf(v.y), f2bf(v.z), f2bf(v.w)};
  *reinterpret_cast<uint2*>(d + (size_t)off*4) = *reinterpret_cast<const uint2*>(t);
}

// ================= 128x128 bf16 GEMM core, 2-phase double-buffered ===========
// SWAP=true flips MFMA operands: acc col(l16)=m(token), row(quad*4+r)=n(feat).
template<bool SWAP>
__device__ __forceinline__ void gemm_core_bf16_glds(
    const ushort_t* __restrict__ A, const ushort_t* __restrict__ B,
    ushort_t* As, ushort_t* Bs,    // each [2][128*32]
    int m0, int n0, f32x4 acc[4][4])
{
  const int tid  = threadIdx.x;
  const int lane = tid & 63;
  const int wave = tid >> 6;
  const int quad = lane >> 4, l16 = lane & 15;
  const int wm = (wave >> 1) * 64, wn = (wave & 1) * 64;

  const int srow0 = tid >> 2, sseg0 = tid & 3;

  #define STAGE_BF16(k0, hb) { \
    _Pragma("unroll") \
    for(int u = 0; u < 2; u++){ \
      int idx = tid + u * 256; \
      int row = srow0 + u * 64, seg = sseg0; \
      int col = (seg ^ (row & 3)) * 8; \
      ushort_t* la = &As[(hb)*4096 + (size_t)(idx & ~63) * 8]; \
      ushort_t* lb = &Bs[(hb)*4096 + (size_t)(idx & ~63) * 8]; \
      GLDS(&A[(size_t)(m0+row)*DM + (k0) + col], la); \
      GLDS(&B[(size_t)(n0+row)*DM + (k0) + col], lb); \
    } }

  STAGE_BF16(0, 0);
  __syncthreads();
  int cur = 0;
  for(int k0 = 0; k0 < DM; k0 += 32){
    if(k0 + 32 < DM) STAGE_BF16(k0 + 32, cur ^ 1);
    const ushort_t* as = &As[cur*4096];
    const ushort_t* bs = &Bs[cur*4096];
    short8 af[4], bf[4];
    #pragma unroll
    for(int mt=0;mt<4;mt++){
      int row = wm + mt*16 + l16;
      af[mt] = *reinterpret_cast<const short8*>(&as[row*32 + (quad ^ (row&3))*8]);
    }
    #pragma unroll
    for(int nt=0;nt<4;nt++){
      int row = wn + nt*16 + l16;
      bf[nt] = *reinterpret_cast<const short8*>(&bs[row*32 + (quad ^ (row&3))*8]);
    }
    #pragma unroll
    for(int mt=0;mt<4;mt++)
      #pragma unroll
      for(int nt=0;nt<4;nt++)
        acc[mt][nt] = SWAP
          ? __builtin_amdgcn_mfma_f32_16x16x32_bf16(bf[nt], af[mt], acc[mt][nt], 0, 0, 0)
          : __builtin_amdgcn_mfma_f32_16x16x32_bf16(af[mt], bf[nt], acc[mt][nt], 0, 0, 0);
    __syncthreads();
    cur ^= 1;
  }
  #undef STAGE_BF16
}

// f32 fallback core (small-ws path only)
template<bool SWAP>
__device__ __forceinline__ void gemm_core_f32(
    const float* __restrict__ A, const float* __restrict__ B,
    ushort_t* As, ushort_t* Bs, int m0, int n0, f32x4 acc[4][4])
{
  const int tid  = threadIdx.x;
  const int lane = tid & 63;
  const int wave = tid >> 6;
  const int quad = lane >> 4, l16 = lane & 15;
  const int wm = (wave >> 1) * 64, wn = (wave & 1) * 64;
  for(int k0 = 0; k0 < DM; k0 += 32){
    #pragma unroll
    for(int u = 0; u < 4; u++){
      int idx = tid + u * 256;
      int row = idx >> 3, seg = idx & 7;
      float4 av = *reinterpret_cast<const float4*>(&A[(size_t)(m0+row)*DM + k0 + seg*4]);
      float4 bv = *reinterpret_cast<const float4*>(&B[(size_t)(n0+row)*DM + k0 + seg*4]);
      ushort_t at[4] = {f2bf(av.x), f2bf(av.y), f2bf(av.z), f2bf(av.w)};
      ushort_t bt[4] = {f2bf(bv.x), f2bf(bv.y), f2bf(bv.z), f2bf(bv.w)};
      *reinterpret_cast<uint2*>(&As[row*40 + seg*4]) = *reinterpret_cast<const uint2*>(at);
      *reinterpret_cast<uint2*>(&Bs[row*40 + seg*4]) = *reinterpret_cast<const uint2*>(bt);
    }
    __syncthreads();
    short8 af[4], bf[4];
    #pragma unroll
    for(int mt=0;mt<4;mt++) af[mt] = *reinterpret_cast<const short8*>(&As[(wm+mt*16+l16)*40 + quad*8]);
    #pragma unroll
    for(int nt=0;nt<4;nt++) bf[nt] = *reinterpret_cast<const short8*>(&Bs[(wn+nt*16+l16)*40 + quad*8]);
    #pragma unroll
    for(int mt=0;mt<4;mt++)
      #pragma unroll
      for(int nt=0;nt<4;nt++)
        acc[mt][nt] = SWAP
          ? __builtin_amdgcn_mfma_f32_16x16x32_bf16(bf[nt], af[mt], acc[mt][nt], 0, 0, 0)
          : __builtin_amdgcn_mfma_f32_16x16x32_bf16(af[mt], bf[nt], acc[mt][nt], 0, 0, 0);
    __syncthreads();
  }
}

// ================= QKV epilogue (all-SWAP): in-thread RoPE ===================
__device__ __forceinline__ void qkv_epilogue_swap(
    int z, int m0, int n0, f32x4 acc[4][4], const float* __restrict__ tab,
    ushort_t* __restrict__ Q, ushort_t* __restrict__ Ko, ushort_t* __restrict__ Vt)
{
  const int lane = threadIdx.x & 63;
  const int wave = threadIdx.x >> 6;
  const int quad = lane >> 4, l16 = lane & 15;
  const int wm = (wave >> 1) * 64, wn = (wave & 1) * 64;
  if(z < 2){
    ushort_t* outp = (z == 0) ? Q : Ko;
    const float qscale = (z == 0) ? 0.125f : 1.0f;   // fold 1/sqrt(64) into Q
    #pragma unroll
    for(int mt=0;mt<4;mt++){
      int m = m0 + wm + mt*16 + l16;      // token
      int b = m >> 11, s = m & 2047;
      #pragma unroll
      for(int nt=0;nt<4;nt++){
        int nbase = n0 + wn + nt*16 + quad*4;   // 4-aligned feature base
        int h  = nbase >> 6, dhb = nbase & 63;
        int jb = dhb & 31;                       // jb..jb+3, no 32-wrap
        float v0 = acc[mt][nt][0], v1 = acc[mt][nt][1];
        float v2 = acc[mt][nt][2], v3 = acc[mt][nt][3];
        float2 cs0 = *reinterpret_cast<const float2*>(&tab[((jb  )*SEQ + s)*2]);
        float2 cs1 = *reinterpret_cast<const float2*>(&tab[((jb+1)*SEQ + s)*2]);
        float2 cs2 = *reinterpret_cast<const float2*>(&tab[((jb+2)*SEQ + s)*2]);
        float2 cs3 = *reinterpret_cast<const float2*>(&tab[((jb+3)*SEQ + s)*2]);
        float oe0 = (v0*cs0.x - v1*cs0.y) * qscale;   // -> outd = dhb/2
        float oo0 = (v0*cs1.y + v1*cs1.x) * qscale;   // -> outd = dhb/2 + 32
        float oe1 = (v2*cs2.x - v3*cs2.y) * qscale;   // -> outd = dhb/2 + 1
        float oo1 = (v2*cs3.y + v3*cs3.x) * qscale;   // -> outd = dhb/2 + 33
        int d2 = dhb >> 1;                             // even
        size_t base = ((size_t)(b*NH + h)*SEQ + s)*HD;
        uint32_t lo = (uint32_t)f2bf_fast(oe0) | ((uint32_t)f2bf_fast(oe1) << 16);
        uint32_t hi = (uint32_t)f2bf_fast(oo0) | ((uint32_t)f2bf_fast(oo1) << 16);
        *reinterpret_cast<uint32_t*>(&outp[base + d2])      = lo;
        *reinterpret_cast<uint32_t*>(&outp[base + d2 + 32]) = hi;
      }
    }
  } else {
    // V^T: col(l16)=token -> 32B-contiguous token segments per (nt,mt,r)
    #pragma unroll
    for(int nt=0;nt<4;nt++){
      #pragma unroll
      for(int mt=0;mt<4;mt++){
        int m = m0 + wm + mt*16 + l16;
        int b = m >> 11, s = m & 2047;
        #pragma unroll
        for(int r=0;r<4;r++){
          int n = n0 + wn + nt*16 + quad*4 + r;
          int h = n >> 6, dh = n & 63;
          Vt[((size_t)(b*NH + h)*HD + dh)*SEQ + s] = f2bf_fast(acc[mt][nt][r]);
        }
      }
    }
  }
}

__global__ __launch_bounds__(256) void qkv_bf16_kernel(
    const ushort_t* __restrict__ xb,
    const ushort_t* __restrict__ wqb, const ushort_t* __restrict__ wkb,
    const ushort_t* __restrict__ wvb, const float* __restrict__ tab,
    ushort_t* __restrict__ Q, ushort_t* __restrict__ Ko, ushort_t* __restrict__ Vt)
{
  const int z = blockIdx.z;
  const ushort_t* W = (z == 0) ? wqb : (z == 1) ? wkb : wvb;
  const int m0 = blockIdx.x * 128, n0 = blockIdx.y * 128;
  __shared__ __align__(16) ushort_t As[2*128*32];
  __shared__ __align__(16) ushort_t Bs[2*128*32];
  f32x4 acc[4][4];
  #pragma unroll
  for(int i=0;i<4;i++)
    #pragma unroll
    for(int j=0;j<4;j++) acc[i][j] = (f32x4){0.f,0.f,0.f,0.f};
  gemm_core_bf16_glds<true>(xb, W, As, Bs, m0, n0, acc);
  qkv_epilogue_swap(z, m0, n0, acc, tab, Q, Ko, Vt);
}

__global__ __launch_bounds__(256) void qkv_f32_kernel(
    const float* __restrict__ x,
    const float* __restrict__ Wq, const float* __restrict__ Wk,
    const float* __restrict__ Wv, const float* __restrict__ tab,
    ushort_t* __restrict__ Q, ushort_t* __restrict__ Ko, ushort_t* __restrict__ Vt)
{
  const int z = blockIdx.z;
  const float* W = (z == 0) ? Wq : (z == 1) ? Wk : Wv;
  const int m0 = blockIdx.x * 128, n0 = blockIdx.y * 128;
  __shared__ __align__(16) char smem[20480];
  ushort_t* As = (ushort_t*)smem;
  ushort_t* Bs = (ushort_t*)(smem + 10240);
  f32x4 acc[4][4];
  #pragma unroll
  for(int i=0;i<4;i++)
    #pragma unroll
    for(int j=0;j<4;j++) acc[i][j] = (f32x4){0.f,0.f,0.f,0.f};
  gemm_core_f32<true>(x, W, As, Bs, m0, n0, acc);
  qkv_epilogue_swap(z, m0, n0, acc, tab, Q, Ko, Vt);
}

// ================= Flash attention, causal — 32 q rows per wave ==============
// FINAL (round-13): exact round-7 kernel — the session's best verified attn
// (79.6 µs; VGPR 108, WRITE 8MB, no spill). r12's s_setprio around MFMA
// clusters REGRESSED -19% (95 µs): with 2 barrier-coupled 4-wave blocks/CU,
// prio-1 MFMA waves starve co-resident waves' staging/softmax issue slots
// (T5 is structure-conditional; m191's win was 1-wave independent blocks).
// Structure: double-buffered K/V LDS, ONE barrier per kv-tile, t+2 register
// prefetch, per-wave P roundtrip, no-max softmax (__expf), g-paired grid.
__global__ __launch_bounds__(256) void attn_kernel(
    ushort_t* __restrict__ Qbuf, const ushort_t* __restrict__ K,
    const ushort_t* __restrict__ Vt)
{
  const int bh = blockIdx.x;            // 0..31
  const int y  = blockIdx.y;            // 0..15
  const int g  = (y < 8) ? (15 - y) : (y - 8);
  const int T  = 2*(g+1);               // 64-kv rounds
  const int tid  = threadIdx.x;
  const int lane = tid & 63;
  const int wave = tid >> 6;            // 0..3
  const int quad = lane >> 4, l16 = lane & 15;

  ushort_t*       Qp = Qbuf + (size_t)bh * SEQ * HD;
  const ushort_t* Kp = K    + (size_t)bh * SEQ * HD;
  const ushort_t* Vp = Vt   + (size_t)bh * HD * SEQ;

  __shared__ __align__(16) ushort_t Ks[2][64*72];
  __shared__ __align__(16) ushort_t Vs[2][64*72];
  __shared__ __align__(16) ushort_t Pl[4][32*72];   // per-wave P roundtrip
  ushort_t* pl = &Pl[wave][0];

  const int srow0 = tid >> 3;           // staging row 0..31 (+32 for u=1)
  const int scol  = (tid & 7) * 8;      // 16B chunk col

  const int q0w = 128*g + 32*wave;      // this wave's 32 q rows

  // Q fragments (B-operand), 2 sets x 2 kk, from global once
  short8 qf[2][2];
  #pragma unroll
  for(int s=0;s<2;s++)
    #pragma unroll
    for(int kk=0;kk<2;kk++)
      qf[s][kk] = *reinterpret_cast<const short8*>(&Qp[(size_t)(q0w + 16*s + l16)*HD + kk*32 + quad*8]);

  f32x4 oacc[2][4];
  #pragma unroll
  for(int s=0;s<2;s++)
    #pragma unroll
    for(int dt=0;dt<4;dt++) oacc[s][dt] = (f32x4){0.f,0.f,0.f,0.f};
  float llane[2] = {0.f, 0.f};

  // prologue: tile 0 -> regs -> buf0; prefetch tile 1 -> regs
  uint4 kreg[2], vreg[2];
  #pragma unroll
  for(int u=0;u<2;u++){
    int row = srow0 + u*32;
    kreg[u] = *reinterpret_cast<const uint4*>(&Kp[(size_t)row*HD + scol]);
    vreg[u] = *reinterpret_cast<const uint4*>(&Vp[(size_t)row*SEQ + scol]);
  }
  #pragma unroll
  for(int u=0;u<2;u++){
    int row = srow0 + u*32;
    *reinterpret_cast<uint4*>(&Ks[0][row*72 + scol]) = kreg[u];
    *reinterpret_cast<uint4*>(&Vs[0][row*72 + scol]) = vreg[u];
  }
  if(T > 1){
    #pragma unroll
    for(int u=0;u<2;u++){
      int row = srow0 + u*32;
      kreg[u] = *reinterpret_cast<const uint4*>(&Kp[(size_t)(64 + row)*HD + scol]);
      vreg[u] = *reinterpret_cast<const uint4*>(&Vp[(size_t)row*SEQ + 64 + scol]);
    }
  }
  __syncthreads();    // buf0 visible

  for(int t = 0; t < T; t++){
    const int kv0 = t * 64;
    const int cur = t & 1;

    // K/V fragments from current buffer — issued first (critical path)
    short8 kf[4][2], vf[4][2];
    #pragma unroll
    for(int nt=0;nt<4;nt++)
      #pragma unroll
      for(int kk=0;kk<2;kk++)
        kf[nt][kk] = *reinterpret_cast<const short8*>(&Ks[cur][(nt*16 + l16)*72 + kk*32 + quad*8]);
    #pragma unroll
    for(int dt=0;dt<4;dt++)
      #pragma unroll
      for(int kk=0;kk<2;kk++)
        vf[dt][kk] = *reinterpret_cast<const short8*>(&Vs[cur][(dt*16 + l16)*72 + kk*32 + quad*8]);

    // stage tile t+1 (regs -> other buffer); overlaps with compute below
    if(t + 1 < T){
      #pragma unroll
      for(int u=0;u<2;u++){
        int row = srow0 + u*32;
        *reinterpret_cast<uint4*>(&Ks[cur^1][row*72 + scol]) = kreg[u];
        *reinterpret_cast<uint4*>(&Vs[cur^1][row*72 + scol]) = vreg[u];
      }
    }
    // prefetch tile t+2 globals into regs (regs free after the ds_writes)
    if(t + 2 < T){
      #pragma unroll
      for(int u=0;u<2;u++){
        int row = srow0 + u*32;
        kreg[u] = *reinterpret_cast<const uint4*>(&Kp[(size_t)(kv0 + 128 + row)*HD + scol]);
        vreg[u] = *reinterpret_cast<const uint4*>(&Vp[(size_t)row*SEQ + kv0 + 128 + scol]);
      }
    }

    #pragma unroll
    for(int s=0;s<2;s++){
      // S^T = K·(Q/8)^T : col=q=l16, row=kv=quad*4+r (block nt*16)
      f32x4 sacc[4];
      #pragma unroll
      for(int nt=0;nt<4;nt++) sacc[nt] = (f32x4){0.f,0.f,0.f,0.f};
      #pragma unroll
      for(int kk=0;kk<2;kk++)
        #pragma unroll
        for(int nt=0;nt<4;nt++)
          sacc[nt] = __builtin_amdgcn_mfma_f32_16x16x32_bf16(kf[nt][kk], qf[s][kk], sacc[nt], 0,0,0);

      const int q_abs = q0w + 16*s + l16;
      const bool maskable = (kv0 + 63 > q0w + 16*s);   // wave-uniform
      float pv[4][4];
      #pragma unroll
      for(int nt=0;nt<4;nt++)
        #pragma unroll
        for(int r=0;r<4;r++){
          float sv = sacc[nt][r];
          if(maskable){
            int kv_abs = kv0 + nt*16 + quad*4 + r;
            sv = (kv_abs > q_abs) ? -1e30f : sv;
          }
          float p = __expf(sv);
          pv[nt][r] = p;
          llane[s] += p;
        }

      // P^T -> per-wave LDS rows 16s..16s+15 (packed b64; same-wave DS order)
      asm volatile("" ::: "memory");
      #pragma unroll
      for(int nt=0;nt<4;nt++){
        uint32_t lo = (uint32_t)f2bf_fast(pv[nt][0]) | ((uint32_t)f2bf_fast(pv[nt][1]) << 16);
        uint32_t hi = (uint32_t)f2bf_fast(pv[nt][2]) | ((uint32_t)f2bf_fast(pv[nt][3]) << 16);
        uint2 pk; pk.x = lo; pk.y = hi;
        *reinterpret_cast<uint2*>(&pl[(16*s + l16)*72 + nt*16 + quad*4]) = pk;
      }
      asm volatile("s_waitcnt lgkmcnt(0)" ::: "memory");

      // PV: out^T += V^T·P^T
      #pragma unroll
      for(int kk=0;kk<2;kk++){
        short8 pf = *reinterpret_cast<const short8*>(&pl[(16*s + l16)*72 + kk*32 + quad*8]);
        #pragma unroll
        for(int dt=0;dt<4;dt++)
          oacc[s][dt] = __builtin_amdgcn_mfma_f32_16x16x32_bf16(vf[dt][kk], pf, oacc[s][dt], 0,0,0);
      }
    }
    __syncthreads();   // all waves done reading buf[cur]; buf[cur^1] staged
  }

  // epilogue: cross-quad l reduce per set, normalize, packed 8B stores
  #pragma unroll
  for(int s=0;s<2;s++){
    float lt = llane[s];
    lt += __shfl_xor(lt, 16);
    lt += __shfl_xor(lt, 32);
    float inv = 1.0f / lt;
    #pragma unroll
    for(int dt=0;dt<4;dt++){
      uint32_t lo = (uint32_t)f2bf_fast(oacc[s][dt][0] * inv) | ((uint32_t)f2bf_fast(oacc[s][dt][1] * inv) << 16);
      uint32_t hi = (uint32_t)f2bf_fast(oacc[s][dt][2] * inv) | ((uint32_t)f2bf_fast(oacc[s][dt][3] * inv) << 16);
      uint2 pk; pk.x = lo; pk.y = hi;
      *reinterpret_cast<uint2*>(&Qp[(size_t)(q0w + 16*s + l16)*HD + dt*16 + quad*4]) = pk;
    }
  }
}

// ================= Output projection (2-phase glds staging) =================
__global__ __launch_bounds__(256) void out_proj_bf16_kernel(
    const ushort_t* __restrict__ ctx, const ushort_t* __restrict__ wob,
    float* __restrict__ out)
{
  const int m0 = blockIdx.x * 128, n0 = blockIdx.y * 128;
  __shared__ __align__(16) ushort_t As[2*128*32];
  __shared__ __align__(16) ushort_t Bs[2*128*32];
  const int tid  = threadIdx.x;
  const int lane = tid & 63;
  const int wave = tid >> 6;
  const int quad = lane >> 4, l16 = lane & 15;
  const int wm = (wave >> 1) * 64, wn = (wave & 1) * 64;
  const int srow0 = tid >> 2, sseg0 = tid & 3;

  f32x4 acc[4][4];
  #pragma unroll
  for(int i=0;i<4;i++)
    #pragma unroll
    for(int j=0;j<4;j++) acc[i][j] = (f32x4){0.f,0.f,0.f,0.f};

  #define STAGE_OP(k0, hb) { \
    const int head = (k0) >> 6, off = (k0) & 63; \
    _Pragma("unroll") \
    for(int u = 0; u < 2; u++){ \
      int idx = tid + u * 256; \
      int row = srow0 + u * 64, seg = sseg0; \
      int col = (seg ^ (row & 3)) * 8; \
      int m = m0 + row, b = m >> 11, s = m & 2047; \
      ushort_t* la = &As[(hb)*4096 + (size_t)(idx & ~63) * 8]; \
      ushort_t* lb = &Bs[(hb)*4096 + (size_t)(idx & ~63) * 8]; \
      GLDS(&ctx[((size_t)(b*NH + head)*SEQ + s)*HD + off + col], la); \
      GLDS(&wob[(size_t)(n0+row)*DM + (k0) + col], lb); \
    } }

  STAGE_OP(0, 0);
  __syncthreads();
  int cur = 0;
  for(int k0 = 0; k0 < DM; k0 += 32){
    if(k0 + 32 < DM) STAGE_OP(k0 + 32, cur ^ 1);
    const ushort_t* as = &As[cur*4096];
    const ushort_t* bs = &Bs[cur*4096];
    short8 af[4], bf[4];
    #pragma unroll
    for(int mt=0;mt<4;mt++){
      int row = wm + mt*16 + l16;
      af[mt] = *reinterpret_cast<const short8*>(&as[row*32 + (quad ^ (row&3))*8]);
    }
    #pragma unroll
    for(int nt=0;nt<4;nt++){
      int row = wn + nt*16 + l16;
      bf[nt] = *reinterpret_cast<const short8*>(&bs[row*32 + (quad ^ (row&3))*8]);
    }
    #pragma unroll
    for(int mt=0;mt<4;mt++)
      #pragma unroll
      for(int nt=0;nt<4;nt++)
        acc[mt][nt] = __builtin_amdgcn_mfma_f32_16x16x32_bf16(af[mt], bf[nt], acc[mt][nt], 0, 0, 0);
    __syncthreads();
    cur ^= 1;
  }
  #undef STAGE_OP

  #pragma unroll
  for(int mt=0;mt<4;mt++)
    #pragma unroll
    for(int nt=0;nt<4;nt++)
      #pragma unroll
      for(int r=0;r<4;r++){
        int m = m0 + wm + mt*16 + quad*4 + r;
        int n = n0 + wn + nt*16 + l16;
        out[(size_t)m*DM + n] = acc[mt][nt][r];
      }
}

__global__ __launch_bounds__(256) void out_proj_f32_kernel(
    const ushort_t* __restrict__ ctx, const float* __restrict__ Wo,
    float* __restrict__ out)
{
  const int m0 = blockIdx.x * 128, n0 = blockIdx.y * 128;
  __shared__ __align__(16) ushort_t As[128*40];
  __shared__ __align__(16) ushort_t Bs[128*40];
  const int tid  = threadIdx.x;
  const int lane = tid & 63;
  const int wave = tid >> 6;
  const int quad = lane >> 4, l16 = lane & 15;
  const int wm = (wave >> 1) * 64, wn = (wave & 1) * 64;

  f32x4 acc[4][4];
  #pragma unroll
  for(int i=0;i<4;i++)
    #pragma unroll
    for(int j=0;j<4;j++) acc[i][j] = (f32x4){0.f,0.f,0.f,0.f};

  for(int k0 = 0; k0 < DM; k0 += 32){
    const int head = k0 >> 6, off = k0 & 63;
    #pragma unroll
    for(int u = 0; u < 2; u++){
      int idx = tid + u * 256;
      int row = idx >> 2, seg = idx & 3;
      int m = m0 + row, b = m >> 11, s = m & 2047;
      *reinterpret_cast<uint4*>(&As[row*40 + seg*8]) =
        *reinterpret_cast<const uint4*>(&ctx[((size_t)(b*NH + head)*SEQ + s)*HD + off + seg*8]);
    }
    #pragma unroll
    for(int u = 0; u < 4; u++){
      int idx = tid + u * 256;
      int row = idx >> 3, seg = idx & 7;
      float4 bv = *reinterpret_cast<const float4*>(&Wo[(size_t)(n0+row)*DM + k0 + seg*4]);
      ushort_t bt[4] = {f2bf(bv.x), f2bf(bv.y), f2bf(bv.z), f2bf(bv.w)};
      *reinterpret_cast<uint2*>(&Bs[row*40 + seg*4]) = *reinterpret_cast<const uint2*>(bt);
    }
    __syncthreads();
    short8 af[4], bf[4];
    #pragma unroll
    for(int mt=0;mt<4;mt++) af[mt] = *reinterpret_cast<const short8*>(&As[(wm+mt*16+l16)*40 + quad*8]);
    #pragma unroll
    for(int nt=0;nt<4;nt++) bf[nt] = *reinterpret_cast<const short8*>(&Bs[(wn+nt*16+l16)*40 + quad*8]);
    #pragma unroll
    for(int mt=0;mt<4;mt++)
      #pragma unroll
      for(int nt=0;nt<4;nt++)
        acc[mt][nt] = __builtin_amdgcn_mfma_f32_16x16x32_bf16(af[mt], bf[nt], acc[mt][nt], 0, 0, 0);
    __syncthreads();
  }
  #pragma unroll
  for(int mt=0;mt<4;mt++)
    #pragma unroll
    for(int nt=0;nt<4;nt++)
      #pragma unroll
      for(int r=0;r<4;r++){
        int m = m0 + wm + mt*16 + quad*4 + r;
        int n = n0 + wn + nt*16 + l16;
        out[(size_t)m*DM + n] = acc[mt][nt][r];
      }
}

extern "C" void kernel_launch(void* const* d_in, const int* in_sizes, int n_in,
                              void* d_out, int out_size, void* d_ws, size_t ws_size,
                              hipStream_t stream) {
  const float* x  = (const float*)d_in[0];
  const float* Wq = (const float*)d_in[1];
  const float* Wk = (const float*)d_in[2];
  const float* Wv = (const float*)d_in[3];
  const float* Wo = (const float*)d_in[4];
  // d_in[5] = attn_mask (tril int32) — implemented positionally as causal.
  float* out = (float*)d_out;

  // ws: Qb 8MB (Q -> ctx in-place) + trig 512KB; big path adds xb + bf16 weights.
  // d_out (16MB fp32): K + V^T bf16 scratch, dead before out_proj writes.
  char* ws = (char*)d_ws;
  ushort_t* Qb  = (ushort_t*)ws;                              // 8 MB
  float*    tab = (float*)(ws + (8u << 20));                  // 512 KB
  ushort_t* Kb  = (ushort_t*)d_out;                           // 8 MB
  ushort_t* Vt  = (ushort_t*)d_out + (size_t)BATCH*NH*SEQ*HD; // 8 MB

  const bool big_ws = ws_size >= (25u << 20);

  if(big_ws){
    ushort_t* xb  = (ushort_t*)(ws + (8u  << 20) + (512u << 10));   // 8 MB
    char*     wb0 = ws + (16u << 20) + (512u << 10);
    ushort_t* wqb = (ushort_t*)(wb0);
    ushort_t* wkb = (ushort_t*)(wb0 + (2u << 20));
    ushort_t* wvb = (ushort_t*)(wb0 + (4u << 20));
    ushort_t* wob = (ushort_t*)(wb0 + (6u << 20));
    prep_kernel<<<8448, 256, 0, stream>>>(x, Wq, Wk, Wv, Wo, xb, wqb, wkb, wvb, wob, tab);
    dim3 g1(32, 8, 3);
    qkv_bf16_kernel<<<g1, 256, 0, stream>>>(xb, wqb, wkb, wvb, tab, Qb, Kb, Vt);
    dim3 g2(32, 16);   // (bh, y): XCD affinity + g-paired balance (r7 grid)
    attn_kernel<<<g2, 256, 0, stream>>>(Qb, Kb, Vt);
    dim3 g3(32, 8);
    out_proj_bf16_kernel<<<g3, 256, 0, stream>>>(Qb, wob, out);
  } else {
    rope_tab_kernel<<<256, 256, 0, stream>>>(tab);
    dim3 g1(32, 8, 3);
    qkv_f32_kernel<<<g1, 256, 0, stream>>>(x, Wq, Wk, Wv, tab, Qb, Kb, Vt);
    dim3 g2(32, 16);
    attn_kernel<<<g2, 256, 0, stream>>>(Qb, Kb, Vt);
    dim3 g3(32, 8);
    out_proj_f32_kernel<<<g3, 256, 0, stream>>>(Qb, Wo, out);
  }
}